// Round 15
// baseline (219.062 us; speedup 1.0000x reference)
//
#include <hip/hip_runtime.h>

// AliasFreeActivation fused kernel, round 15 (base = r13):
//  - B's 6-tap accumulation forced to v_pk_fma_f32 (VOP3P) via inline asm.
//    r14 lesson: packed-f32 sources are 64-bit operands -> pass the tap as an
//    f2 {f,f} with "s" constraint (even-aligned SGPR pair), no op_sel needed.
//  - separate gpkD (= sqrt2 * gpk) used ONLY by D (C keeps plain gpk)
//  - keeps r13: LDS 20160B -> 8 blocks/CU, f16 act/t2t, dot2 C/D, packed-f16
//    leaky, direct-global A, bias fold, edge fast paths
//
// Math (verified rounds 1-13):
//  A  h-up:   t1[r][u]=sum_t f[k0+4t]*xw[bb-t], u=8ug+du, k0=(du+1)&3,
//             bb=((du+25-k0)>>2)-1, window x cols [2ug,2ug+7]. No bias.
//  B  v-up:   act[v][:]=leaky( sum_t f[k0+4t]*w[bb-t][:] + bc[k0] );
//             v=8vt8+dv (<74), k0=(dv+1)&3, bb=5+((dv+1)>>2), w[m]=t1[2vt8+m].
//  C  h-down: t2t[o][v]=sum_m dot2(actdw[i+m],gpk[m]), o=8otg+i,
//             window dwords [8otg..8otg+12].
//  D  v-down: out[4g+dv][ox]=sum_m dot2(t2tdw[dv+m],gpkD[m]) (sqrt2 in gpkD),
//             window t2t dwords [4g..4g+8].
//
// LDS (bytes): act f16 74x80 @0 (11840) | t1 f32 26x80w @11840 (8320)
//              t2t f16 32x88 @11840 (5632, aliases t1, live after C).
//              Total 20160 B -> 8 blocks/CU.

typedef float   f4 __attribute__((ext_vector_type(4)));
typedef float   f2 __attribute__((ext_vector_type(2)));
typedef _Float16 h2 __attribute__((ext_vector_type(2)));

#define ACT_SB   160      // act row stride bytes (80 f16)
#define T1_OFF   11840
#define T1S4     20       // t1 stride in f4 units (80 words)
#define T2T_SB   176      // t2t row stride bytes (88 f16)
#define LDS_B    20160

static __device__ __forceinline__ h2 as_h2(unsigned u) {
    union { unsigned u; h2 h; } x; x.u = u; return x.h;
}
static __device__ __forceinline__ unsigned pkrtz_u32(float lo, float hi) {
    union { __fp16 __attribute__((ext_vector_type(2))) h; unsigned u; } x;
    x.h = __builtin_amdgcn_cvt_pkrtz(lo, hi);
    return x.u;
}
// packed-f16 leaky: max(x, 0.2*x)
static __device__ __forceinline__ unsigned leaky_pk(unsigned x, unsigned c02) {
    unsigned t, r;
    asm("v_pk_mul_f16 %0, %1, %2" : "=v"(t) : "v"(x), "v"(c02));
    asm("v_pk_max_f16 %0, %1, %2" : "=v"(r) : "v"(x), "v"(t));
    return r;
}
// packed f32 fma: acc += w * fpair, fpair = {f,f} in an SGPR pair (64-bit
// VOP3P source; single 32-bit SGPR is not encodable -- r14 lesson).
static __device__ __forceinline__ void pk_fma(f2& acc, f2 w, f2 fpair) {
    asm("v_pk_fma_f32 %0, %1, %2, %0" : "+v"(acc) : "v"(w), "s"(fpair));
}

__global__ __launch_bounds__(256, 8) void afa_kernel(
    const float* __restrict__ x, const float* __restrict__ bias,
    const float* __restrict__ fup, const float* __restrict__ fdn,
    float* __restrict__ out)
{
    __shared__ __align__(16) unsigned char smem[LDS_B];
    f4* const t14 = (f4*)(smem + T1_OFF);

    const int tid   = threadIdx.x;
    const int blk   = blockIdx.x;
    const int plane = blk >> 6;
    const int tile  = blk & 63;
    const int ty = tile >> 3, tx = tile & 7;
    const bool edge = (tx == 7) || (ty == 7);

    float fr[24], gr[12];
    #pragma unroll
    for (int i = 0; i < 24; ++i) fr[i] = fup[i];
    #pragma unroll
    for (int i = 0; i < 12; ++i) gr[i] = fdn[i];

    // dot2 filter pairs: gpk (C, plain) and gpkD (D, sqrt2-folded)
    h2 gpk[6], gpkD[6];
    #pragma unroll
    for (int m = 0; m < 6; ++m) {
        h2 p, pd;
        p.x  = (_Float16)gr[11 - 2 * m];
        p.y  = (_Float16)gr[10 - 2 * m];
        pd.x = (_Float16)(gr[11 - 2 * m] * 1.4142135623730951f);
        pd.y = (_Float16)(gr[10 - 2 * m] * 1.4142135623730951f);
        gpk[m] = p;
        gpkD[m] = pd;
    }
    const unsigned c02 = 0x32663266u;   // (0.2h, 0.2h)

    // bias fold: up(x+b) = up(x) + b*s[k0u]*s[k0v], s[p]=sum_t f[p+4t]
    const float s0 = fr[0] + fr[4] + fr[8]  + fr[12] + fr[16] + fr[20];
    const float s1 = fr[1] + fr[5] + fr[9]  + fr[13] + fr[17] + fr[21];
    const float s2 = fr[2] + fr[6] + fr[10] + fr[14] + fr[18] + fr[22];
    const float s3 = fr[3] + fr[7] + fr[11] + fr[15] + fr[19] + fr[23];
    const float b  = bias[plane & 255];
    const f4 su4 = {s1, s2, s3, s0};              // s[(cc+1)&3]
    f4 bc[4];
    bc[0] = su4 * (b * s0);
    bc[1] = su4 * (b * s1);
    bc[2] = su4 * (b * s2);
    bc[3] = su4 * (b * s3);

    const int iy_base = 16 * ty + 1;
    const int ix_base = 16 * tx + 1;
    const float* xp = x + (size_t)plane * (128 * 128);

    // ---- A: horizontal upsample, direct global reads -> t1 (26 x 80) ----
    for (int task = tid; task < 260; task += 256) {
        const int r = task / 10, ug = task - r * 10;
        float xw[8];
        if (!edge) {
            const float* row = xp + (iy_base + r) * 128 + (ix_base + 2 * ug);
            #pragma unroll
            for (int m = 0; m < 8; ++m) xw[m] = row[m];
        } else {
            const int iy = min(iy_base + r, 127);
            const float* row = xp + iy * 128;
            const int ix0 = ix_base + 2 * ug;
            #pragma unroll
            for (int m = 0; m < 8; ++m) xw[m] = row[min(ix0 + m, 127)];
        }
        f4 res0, res1;
        #pragma unroll
        for (int du = 0; du < 8; ++du) {
            const int k0 = (du + 1) & 3;
            const int bb = ((du + 25 - k0) >> 2) - 1;
            float acc = 0.f;
            #pragma unroll
            for (int t = 0; t < 6; ++t) acc += fr[k0 + 4 * t] * xw[bb - t];
            if (du < 4) res0[du] = acc; else res1[du - 4] = acc;
        }
        t14[r * T1S4 + 2 * ug]     = res0;
        t14[r * T1S4 + 2 * ug + 1] = res1;
    }
    __syncthreads();

    // ---- B: vertical upsample (v_pk_fma_f32) + bias, pack f16, leaky ----
    if (tid < 190) {
        // broadcast taps to 64-bit pairs (uniform -> SGPR pairs)
        f2 frp[24];
        #pragma unroll
        for (int i = 0; i < 24; ++i) frp[i] = f2{fr[i], fr[i]};

        const int vt8 = tid / 19, ut = tid - vt8 * 19;
        f4 w[8];
        #pragma unroll
        for (int m = 0; m < 8; ++m)
            w[m] = t14[(2 * vt8 + m) * T1S4 + ut];
        f2 wl[8], wh[8];
        #pragma unroll
        for (int m = 0; m < 8; ++m) {
            wl[m] = f2{w[m][0], w[m][1]};
            wh[m] = f2{w[m][2], w[m][3]};
        }
        #pragma unroll
        for (int dv = 0; dv < 8; ++dv) {
            const int row = 8 * vt8 + dv;
            if (row < 74) {
                const int k0 = (dv + 1) & 3;
                const int bb = 5 + ((dv + 1) >> 2);
                f2 al = {bc[k0][0], bc[k0][1]};
                f2 ah = {bc[k0][2], bc[k0][3]};
                #pragma unroll
                for (int t = 0; t < 6; ++t) {
                    pk_fma(al, wl[bb - t], frp[k0 + 4 * t]);
                    pk_fma(ah, wh[bb - t], frp[k0 + 4 * t]);
                }
                uint2 pp;
                pp.x = leaky_pk(pkrtz_u32(al[0], al[1]), c02);
                pp.y = leaky_pk(pkrtz_u32(ah[0], ah[1]), c02);
                *(uint2*)(smem + row * ACT_SB + 8 * ut) = pp;
            }
        }
    }
    __syncthreads();

    // ---- C: horizontal downsample via dot2 -> t2t f16 [o][v] (transposed) ----
    {
        // batch 1: rows 0..63, all 256 threads
        const int v = tid & 63, otg = tid >> 6;
        {
            const unsigned* ar = (const unsigned*)(smem + v * ACT_SB + 32 * otg);
            uint4 q0 = *(const uint4*)(ar);
            uint4 q1 = *(const uint4*)(ar + 4);
            uint4 q2 = *(const uint4*)(ar + 8);
            const unsigned dl = ar[12];
            unsigned d[13] = {q0.x,q0.y,q0.z,q0.w, q1.x,q1.y,q1.z,q1.w,
                              q2.x,q2.y,q2.z,q2.w, dl};
            #pragma unroll
            for (int i = 0; i < 8; ++i) {
                float acc = 0.f;
                #pragma unroll
                for (int m = 0; m < 6; ++m)
                    acc = __builtin_amdgcn_fdot2(as_h2(d[i + m]), gpk[m], acc, false);
                _Float16 hv = (_Float16)acc;
                *(_Float16*)(smem + T1_OFF + (8*otg + i) * T2T_SB + 2*v) = hv;
            }
        }
        // batch 2: rows 64..73
        if (tid < 64) {
            const int otg2 = tid >> 4, vr = tid & 15;
            if (vr < 10) {
                const int v2 = 64 + vr;
                const unsigned* ar = (const unsigned*)(smem + v2 * ACT_SB + 32 * otg2);
                uint4 q0 = *(const uint4*)(ar);
                uint4 q1 = *(const uint4*)(ar + 4);
                uint4 q2 = *(const uint4*)(ar + 8);
                const unsigned dl = ar[12];
                unsigned d[13] = {q0.x,q0.y,q0.z,q0.w, q1.x,q1.y,q1.z,q1.w,
                                  q2.x,q2.y,q2.z,q2.w, dl};
                #pragma unroll
                for (int i = 0; i < 8; ++i) {
                    float acc = 0.f;
                    #pragma unroll
                    for (int m = 0; m < 6; ++m)
                        acc = __builtin_amdgcn_fdot2(as_h2(d[i + m]), gpk[m], acc, false);
                    _Float16 hv = (_Float16)acc;
                    *(_Float16*)(smem + T1_OFF + (8*otg2 + i) * T2T_SB + 2*v2) = hv;
                }
            }
        }
    }
    __syncthreads();

    // ---- D: vertical downsample via dot2 (sqrt2 in gpkD), store to global ----
    {
        const int oy0 = ty * 32, ox0 = tx * 32;
        float* op = out + (size_t)plane * (236 * 236);
        const int ox = tid & 31, g = tid >> 5;
        const unsigned* tr = (const unsigned*)(smem + T1_OFF + ox * T2T_SB + 16 * g);
        uint4 q0 = *(const uint4*)(tr);
        uint4 q1 = *(const uint4*)(tr + 4);
        const unsigned dl = tr[8];
        unsigned d[9] = {q0.x, q0.y, q0.z, q0.w, q1.x, q1.y, q1.z, q1.w, dl};
        const int oxg = ox0 + ox;
        if (!edge) {
            #pragma unroll
            for (int dv = 0; dv < 4; ++dv) {
                float acc = 0.f;
                #pragma unroll
                for (int m = 0; m < 6; ++m)
                    acc = __builtin_amdgcn_fdot2(as_h2(d[dv + m]), gpkD[m], acc, false);
                op[(oy0 + 4 * g + dv) * 236 + oxg] = acc;
            }
        } else {
            #pragma unroll
            for (int dv = 0; dv < 4; ++dv) {
                float acc = 0.f;
                #pragma unroll
                for (int m = 0; m < 6; ++m)
                    acc = __builtin_amdgcn_fdot2(as_h2(d[dv + m]), gpkD[m], acc, false);
                const int oy = oy0 + 4 * g + dv;
                if (oy < 236 && oxg < 236)
                    op[oy * 236 + oxg] = acc;
            }
        }
    }
}

extern "C" void kernel_launch(void* const* d_in, const int* in_sizes, int n_in,
                              void* d_out, int out_size, void* d_ws, size_t ws_size,
                              hipStream_t stream) {
    const float* x    = (const float*)d_in[0];
    const float* bias = (const float*)d_in[1];
    const float* fup  = (const float*)d_in[2];
    const float* fdn  = (const float*)d_in[3];
    float* out = (float*)d_out;

    dim3 grid(1024 * 64);
    dim3 block(256);
    afa_kernel<<<grid, block, 0, stream>>>(x, bias, fup, fdn, out);
}

// Round 17
// 217.450 us; speedup vs baseline: 1.0074x; 1.0074x over previous
//
#include <hip/hip_runtime.h>

// AliasFreeActivation fused kernel, round 17 (base = r13, the 206µs best):
//  - act rows get a FOOTPRINT-PRESERVING within-row 16B-block swizzle:
//    physical block = logical block XOR s(v), s(v)=(v^(v>>2))&1.
//    (r16 lesson: additive row offsets with stride 160 overlap rows; a
//    within-row permutation cannot.) C's b128 act reads go from 4 span-starts
//    (16-way) to 8 span-starts (8-way = b128 floor).
//  - gpkD = sqrt2*gpk used ONLY in D (C keeps gpk)  [r15-verified safe]
//  - keeps r13: LDS 20160B -> 8 blocks/CU, f16 act/t2t, dot2 C/D, packed-f16
//    leaky, direct-global A, bias fold, edge fast paths
//
// Math (verified rounds 1-13):
//  A  h-up:   t1[r][u]=sum_t f[k0+4t]*xw[bb-t], u=8ug+du, k0=(du+1)&3,
//             bb=((du+25-k0)>>2)-1, window x cols [2ug,2ug+7]. No bias.
//  B  v-up:   act[v][:]=leaky( sum_t f[k0+4t]*w[bb-t][:] + bc[k0] );
//             v=8vt8+dv (<74), k0=(dv+1)&3, bb=5+((dv+1)>>2), w[m]=t1[2vt8+m].
//             write dwords 2ut,2ut+1 -> block ut>>1 ^ s(v), 8B offset (ut&1).
//  C  h-down: t2t[o][v]=sum_m dot2(actdw[i+m],gpk[m]), o=8otg+i; logical
//             blocks 2otg..2otg+3 read at physical (2otg+j)^s(v).
//  D  v-down: out[4g+dv][ox]=sum_m dot2(t2tdw[dv+m],gpkD[m]) (sqrt2 in gpkD),
//             window t2t dwords [4g..4g+8].
//
// LDS (bytes): act f16 74x80 @0 (11840, block-swizzled) | t1 f32 26x80w
//              @11840 (8320) | t2t f16 32x88 @11840 (5632, aliases t1).
//              Total 20160 B -> 8 blocks/CU.

typedef float   f4 __attribute__((ext_vector_type(4)));
typedef float   f2 __attribute__((ext_vector_type(2)));
typedef _Float16 h2 __attribute__((ext_vector_type(2)));

#define ACT_SB   160      // act row stride bytes (80 f16)
#define T1_OFF   11840
#define T1S4     20       // t1 stride in f4 units (80 words)
#define T2T_SB   176      // t2t row stride bytes (88 f16)
#define LDS_B    20160
#define SWZ(v)   (((v) ^ ((v) >> 2)) & 1)

static __device__ __forceinline__ h2 as_h2(unsigned u) {
    union { unsigned u; h2 h; } x; x.u = u; return x.h;
}
static __device__ __forceinline__ unsigned pkrtz_u32(float lo, float hi) {
    union { __fp16 __attribute__((ext_vector_type(2))) h; unsigned u; } x;
    x.h = __builtin_amdgcn_cvt_pkrtz(lo, hi);
    return x.u;
}
// packed-f16 leaky: max(x, 0.2*x)
static __device__ __forceinline__ unsigned leaky_pk(unsigned x, unsigned c02) {
    unsigned t, r;
    asm("v_pk_mul_f16 %0, %1, %2" : "=v"(t) : "v"(x), "v"(c02));
    asm("v_pk_max_f16 %0, %1, %2" : "=v"(r) : "v"(x), "v"(t));
    return r;
}

__global__ __launch_bounds__(256, 8) void afa_kernel(
    const float* __restrict__ x, const float* __restrict__ bias,
    const float* __restrict__ fup, const float* __restrict__ fdn,
    float* __restrict__ out)
{
    __shared__ __align__(16) unsigned char smem[LDS_B];
    f4* const t14 = (f4*)(smem + T1_OFF);

    const int tid   = threadIdx.x;
    const int blk   = blockIdx.x;
    const int plane = blk >> 6;
    const int tile  = blk & 63;
    const int ty = tile >> 3, tx = tile & 7;
    const bool edge = (tx == 7) || (ty == 7);

    float fr[24], gr[12];
    #pragma unroll
    for (int i = 0; i < 24; ++i) fr[i] = fup[i];
    #pragma unroll
    for (int i = 0; i < 12; ++i) gr[i] = fdn[i];

    // dot2 filter pairs: gpk (C, plain) and gpkD (D, sqrt2-folded)
    h2 gpk[6], gpkD[6];
    #pragma unroll
    for (int m = 0; m < 6; ++m) {
        h2 p, pd;
        p.x  = (_Float16)gr[11 - 2 * m];
        p.y  = (_Float16)gr[10 - 2 * m];
        pd.x = (_Float16)(gr[11 - 2 * m] * 1.4142135623730951f);
        pd.y = (_Float16)(gr[10 - 2 * m] * 1.4142135623730951f);
        gpk[m] = p;
        gpkD[m] = pd;
    }
    const unsigned c02 = 0x32663266u;   // (0.2h, 0.2h)

    // bias fold: up(x+b) = up(x) + b*s[k0u]*s[k0v], s[p]=sum_t f[p+4t]
    const float s0 = fr[0] + fr[4] + fr[8]  + fr[12] + fr[16] + fr[20];
    const float s1 = fr[1] + fr[5] + fr[9]  + fr[13] + fr[17] + fr[21];
    const float s2 = fr[2] + fr[6] + fr[10] + fr[14] + fr[18] + fr[22];
    const float s3 = fr[3] + fr[7] + fr[11] + fr[15] + fr[19] + fr[23];
    const float b  = bias[plane & 255];
    const f4 su4 = {s1, s2, s3, s0};              // s[(cc+1)&3]
    f4 bc[4];
    bc[0] = su4 * (b * s0);
    bc[1] = su4 * (b * s1);
    bc[2] = su4 * (b * s2);
    bc[3] = su4 * (b * s3);

    const int iy_base = 16 * ty + 1;
    const int ix_base = 16 * tx + 1;
    const float* xp = x + (size_t)plane * (128 * 128);

    // ---- A: horizontal upsample, direct global reads -> t1 (26 x 80) ----
    for (int task = tid; task < 260; task += 256) {
        const int r = task / 10, ug = task - r * 10;
        float xw[8];
        if (!edge) {
            const float* row = xp + (iy_base + r) * 128 + (ix_base + 2 * ug);
            #pragma unroll
            for (int m = 0; m < 8; ++m) xw[m] = row[m];
        } else {
            const int iy = min(iy_base + r, 127);
            const float* row = xp + iy * 128;
            const int ix0 = ix_base + 2 * ug;
            #pragma unroll
            for (int m = 0; m < 8; ++m) xw[m] = row[min(ix0 + m, 127)];
        }
        f4 res0, res1;
        #pragma unroll
        for (int du = 0; du < 8; ++du) {
            const int k0 = (du + 1) & 3;
            const int bb = ((du + 25 - k0) >> 2) - 1;
            float acc = 0.f;
            #pragma unroll
            for (int t = 0; t < 6; ++t) acc += fr[k0 + 4 * t] * xw[bb - t];
            if (du < 4) res0[du] = acc; else res1[du - 4] = acc;
        }
        t14[r * T1S4 + 2 * ug]     = res0;
        t14[r * T1S4 + 2 * ug + 1] = res1;
    }
    __syncthreads();

    // ---- B: vertical upsample + bias, pack f16, leaky in f16 -> act ----
    if (tid < 190) {
        const int vt8 = tid / 19, ut = tid - vt8 * 19;
        f4 w[8];
        #pragma unroll
        for (int m = 0; m < 8; ++m)
            w[m] = t14[(2 * vt8 + m) * T1S4 + ut];
        f2 wl[8], wh[8];
        #pragma unroll
        for (int m = 0; m < 8; ++m) {
            wl[m] = f2{w[m][0], w[m][1]};
            wh[m] = f2{w[m][2], w[m][3]};
        }
        #pragma unroll
        for (int dv = 0; dv < 8; ++dv) {
            const int row = 8 * vt8 + dv;
            if (row < 74) {
                const int k0 = (dv + 1) & 3;
                const int bb = 5 + ((dv + 1) >> 2);
                f2 al = {bc[k0][0], bc[k0][1]};
                f2 ah = {bc[k0][2], bc[k0][3]};
                #pragma unroll
                for (int t = 0; t < 6; ++t) {
                    al += fr[k0 + 4 * t] * wl[bb - t];
                    ah += fr[k0 + 4 * t] * wh[bb - t];
                }
                uint2 pp;
                pp.x = leaky_pk(pkrtz_u32(al[0], al[1]), c02);
                pp.y = leaky_pk(pkrtz_u32(ah[0], ah[1]), c02);
                const int sw = SWZ(row);
                *(uint2*)(smem + row * ACT_SB
                          + ((((ut >> 1) ^ sw) << 4) | ((ut & 1) << 3))) = pp;
            }
        }
    }
    __syncthreads();

    // ---- C: horizontal downsample via dot2 -> t2t f16 [o][v] (transposed) ----
    {
        // batch 1: rows 0..63, all 256 threads
        const int v = tid & 63, otg = tid >> 6;
        {
            const int sw = SWZ(v);
            const unsigned char* rb = smem + v * ACT_SB;
            const uint4 q0 = *(const uint4*)(rb + (((2*otg + 0) ^ sw) << 4));
            const uint4 q1 = *(const uint4*)(rb + (((2*otg + 1) ^ sw) << 4));
            const uint4 q2 = *(const uint4*)(rb + (((2*otg + 2) ^ sw) << 4));
            const unsigned dl = *(const unsigned*)(rb + (((2*otg + 3) ^ sw) << 4));
            unsigned d[13] = {q0.x,q0.y,q0.z,q0.w, q1.x,q1.y,q1.z,q1.w,
                              q2.x,q2.y,q2.z,q2.w, dl};
            #pragma unroll
            for (int i = 0; i < 8; ++i) {
                float acc = 0.f;
                #pragma unroll
                for (int m = 0; m < 6; ++m)
                    acc = __builtin_amdgcn_fdot2(as_h2(d[i + m]), gpk[m], acc, false);
                _Float16 hv = (_Float16)acc;
                *(_Float16*)(smem + T1_OFF + (8*otg + i) * T2T_SB + 2*v) = hv;
            }
        }
        // batch 2: rows 64..73
        if (tid < 64) {
            const int otg2 = tid >> 4, vr = tid & 15;
            if (vr < 10) {
                const int v2 = 64 + vr;
                const int sw = SWZ(v2);
                const unsigned char* rb = smem + v2 * ACT_SB;
                const uint4 q0 = *(const uint4*)(rb + (((2*otg2 + 0) ^ sw) << 4));
                const uint4 q1 = *(const uint4*)(rb + (((2*otg2 + 1) ^ sw) << 4));
                const uint4 q2 = *(const uint4*)(rb + (((2*otg2 + 2) ^ sw) << 4));
                const unsigned dl = *(const unsigned*)(rb + (((2*otg2 + 3) ^ sw) << 4));
                unsigned d[13] = {q0.x,q0.y,q0.z,q0.w, q1.x,q1.y,q1.z,q1.w,
                                  q2.x,q2.y,q2.z,q2.w, dl};
                #pragma unroll
                for (int i = 0; i < 8; ++i) {
                    float acc = 0.f;
                    #pragma unroll
                    for (int m = 0; m < 6; ++m)
                        acc = __builtin_amdgcn_fdot2(as_h2(d[i + m]), gpk[m], acc, false);
                    _Float16 hv = (_Float16)acc;
                    *(_Float16*)(smem + T1_OFF + (8*otg2 + i) * T2T_SB + 2*v2) = hv;
                }
            }
        }
    }
    __syncthreads();

    // ---- D: vertical downsample via dot2 (sqrt2 in gpkD), store to global ----
    {
        const int oy0 = ty * 32, ox0 = tx * 32;
        float* op = out + (size_t)plane * (236 * 236);
        const int ox = tid & 31, g = tid >> 5;
        const unsigned* tr = (const unsigned*)(smem + T1_OFF + ox * T2T_SB + 16 * g);
        uint4 q0 = *(const uint4*)(tr);
        uint4 q1 = *(const uint4*)(tr + 4);
        const unsigned dl = tr[8];
        unsigned d[9] = {q0.x, q0.y, q0.z, q0.w, q1.x, q1.y, q1.z, q1.w, dl};
        const int oxg = ox0 + ox;
        if (!edge) {
            #pragma unroll
            for (int dv = 0; dv < 4; ++dv) {
                float acc = 0.f;
                #pragma unroll
                for (int m = 0; m < 6; ++m)
                    acc = __builtin_amdgcn_fdot2(as_h2(d[dv + m]), gpkD[m], acc, false);
                op[(oy0 + 4 * g + dv) * 236 + oxg] = acc;
            }
        } else {
            #pragma unroll
            for (int dv = 0; dv < 4; ++dv) {
                float acc = 0.f;
                #pragma unroll
                for (int m = 0; m < 6; ++m)
                    acc = __builtin_amdgcn_fdot2(as_h2(d[dv + m]), gpkD[m], acc, false);
                const int oy = oy0 + 4 * g + dv;
                if (oy < 236 && oxg < 236)
                    op[oy * 236 + oxg] = acc;
            }
        }
    }
}

extern "C" void kernel_launch(void* const* d_in, const int* in_sizes, int n_in,
                              void* d_out, int out_size, void* d_ws, size_t ws_size,
                              hipStream_t stream) {
    const float* x    = (const float*)d_in[0];
    const float* bias = (const float*)d_in[1];
    const float* fup  = (const float*)d_in[2];
    const float* fdn  = (const float*)d_in[3];
    float* out = (float*)d_out;

    dim3 grid(1024 * 64);
    dim3 block(256);
    afa_kernel<<<grid, block, 0, stream>>>(x, bias, fup, fdn, out);
}

// Round 18
// 204.861 us; speedup vs baseline: 1.0693x; 1.0615x over previous
//
#include <hip/hip_runtime.h>

// AliasFreeActivation fused kernel, round 18 = round 13 verbatim (best: 206µs).
// r14-r17 post-mortems: pk_fma asm (+13µs), MFMA-chain (+124µs), row-offset
// swizzle (broken), XOR block swizzle (+11µs) -- all regressed vs this.
// Diagnosis: VALU-issue bound at 8 blocks/CU occupancy; compiler codegen of
// this source is the empirical optimum found.
//  - LDS 20160 B (act stride 80 halfs, t1 stride 80 words) -> 8 blocks/CU,
//    launch_bounds(256,8)
//  - leaky applied in packed f16 AFTER pkrtz: max(x, 0.2x) via v_pk_mul/max_f16
//  - direct-global A, bias fold, f16 act/t2t, dot2 C/D, edge fast paths
//
// Math (verified rounds 1-13):
//  A  h-up:   t1[r][u]=sum_t f[k0+4t]*xw[bb-t], u=8ug+du, k0=(du+1)&3,
//             bb=((du+25-k0)>>2)-1, window x cols [2ug,2ug+7]. No bias.
//  B  v-up:   act[v][:]=leaky( sum_t f[k0+4t]*w[bb-t][:] + bc[k0] );
//             v=8vt8+dv (<74), k0=(dv+1)&3, bb=5+((dv+1)>>2), w[m]=t1[2vt8+m].
//  C  h-down: t2t[o][v]=sum_k g[k]*act[v][2o+11-k] = sum_m dot2(actdw[i+m],gpk[m])
//             for o=8otg+i, window dwords [8otg..8otg+12].
//  D  v-down: out[4g+dv][ox]=sqrt2*sum_m dot2(t2tdw[dv+m],gpk[m]),
//             window t2t dwords [4g..4g+8].
//
// LDS (bytes): act f16 74x80 @0 (11840) | t1 f32 26x80w @11840 (8320)
//              t2t f16 32x88 @11840 (5632, aliases t1, live after C).
//              Total 20160 B -> 8 blocks/CU.

typedef float   f4 __attribute__((ext_vector_type(4)));
typedef float   f2 __attribute__((ext_vector_type(2)));
typedef _Float16 h2 __attribute__((ext_vector_type(2)));

#define ACT_SB   160      // act row stride bytes (80 f16)
#define T1_OFF   11840
#define T1S4     20       // t1 stride in f4 units (80 words)
#define T2T_SB   176      // t2t row stride bytes (88 f16)
#define LDS_B    20160

static __device__ __forceinline__ h2 as_h2(unsigned u) {
    union { unsigned u; h2 h; } x; x.u = u; return x.h;
}
static __device__ __forceinline__ unsigned pkrtz_u32(float lo, float hi) {
    union { __fp16 __attribute__((ext_vector_type(2))) h; unsigned u; } x;
    x.h = __builtin_amdgcn_cvt_pkrtz(lo, hi);
    return x.u;
}
// packed-f16 leaky: max(x, 0.2*x)  (x>=0 -> x ; x<0 -> 0.2x)
static __device__ __forceinline__ unsigned leaky_pk(unsigned x, unsigned c02) {
    unsigned t, r;
    asm("v_pk_mul_f16 %0, %1, %2" : "=v"(t) : "v"(x), "v"(c02));
    asm("v_pk_max_f16 %0, %1, %2" : "=v"(r) : "v"(x), "v"(t));
    return r;
}

__global__ __launch_bounds__(256, 8) void afa_kernel(
    const float* __restrict__ x, const float* __restrict__ bias,
    const float* __restrict__ fup, const float* __restrict__ fdn,
    float* __restrict__ out)
{
    __shared__ __align__(16) unsigned char smem[LDS_B];
    f4* const t14 = (f4*)(smem + T1_OFF);

    const int tid   = threadIdx.x;
    const int blk   = blockIdx.x;
    const int plane = blk >> 6;
    const int tile  = blk & 63;
    const int ty = tile >> 3, tx = tile & 7;
    const bool edge = (tx == 7) || (ty == 7);

    float fr[24], gr[12];
    #pragma unroll
    for (int i = 0; i < 24; ++i) fr[i] = fup[i];
    #pragma unroll
    for (int i = 0; i < 12; ++i) gr[i] = fdn[i];

    // dot2 filter pairs: gpk[m] = (g[11-2m], g[10-2m])  -- NO sqrt2 here,
    // gpk is used by BOTH C and D; sqrt2 applied once in D's epilogue.
    h2 gpk[6];
    #pragma unroll
    for (int m = 0; m < 6; ++m) {
        h2 p;
        p.x = (_Float16)gr[11 - 2 * m];
        p.y = (_Float16)gr[10 - 2 * m];
        gpk[m] = p;
    }
    const unsigned c02 = 0x32663266u;   // (0.2h, 0.2h)

    // bias fold: up(x+b) = up(x) + b*s[k0u]*s[k0v], s[p]=sum_t f[p+4t]
    const float s0 = fr[0] + fr[4] + fr[8]  + fr[12] + fr[16] + fr[20];
    const float s1 = fr[1] + fr[5] + fr[9]  + fr[13] + fr[17] + fr[21];
    const float s2 = fr[2] + fr[6] + fr[10] + fr[14] + fr[18] + fr[22];
    const float s3 = fr[3] + fr[7] + fr[11] + fr[15] + fr[19] + fr[23];
    const float b  = bias[plane & 255];
    const f4 su4 = {s1, s2, s3, s0};              // s[(cc+1)&3]
    f4 bc[4];
    bc[0] = su4 * (b * s0);
    bc[1] = su4 * (b * s1);
    bc[2] = su4 * (b * s2);
    bc[3] = su4 * (b * s3);

    const int iy_base = 16 * ty + 1;
    const int ix_base = 16 * tx + 1;
    const float* xp = x + (size_t)plane * (128 * 128);

    // ---- A: horizontal upsample, direct global reads -> t1 (26 x 80) ----
    for (int task = tid; task < 260; task += 256) {
        const int r = task / 10, ug = task - r * 10;
        float xw[8];
        if (!edge) {
            const float* row = xp + (iy_base + r) * 128 + (ix_base + 2 * ug);
            #pragma unroll
            for (int m = 0; m < 8; ++m) xw[m] = row[m];
        } else {
            const int iy = min(iy_base + r, 127);
            const float* row = xp + iy * 128;
            const int ix0 = ix_base + 2 * ug;
            #pragma unroll
            for (int m = 0; m < 8; ++m) xw[m] = row[min(ix0 + m, 127)];
        }
        f4 res0, res1;
        #pragma unroll
        for (int du = 0; du < 8; ++du) {
            const int k0 = (du + 1) & 3;
            const int bb = ((du + 25 - k0) >> 2) - 1;
            float acc = 0.f;
            #pragma unroll
            for (int t = 0; t < 6; ++t) acc += fr[k0 + 4 * t] * xw[bb - t];
            if (du < 4) res0[du] = acc; else res1[du - 4] = acc;
        }
        t14[r * T1S4 + 2 * ug]     = res0;
        t14[r * T1S4 + 2 * ug + 1] = res1;
    }
    __syncthreads();

    // ---- B: vertical upsample + bias, pack f16, leaky in f16 -> act ----
    if (tid < 190) {
        const int vt8 = tid / 19, ut = tid - vt8 * 19;
        f4 w[8];
        #pragma unroll
        for (int m = 0; m < 8; ++m)
            w[m] = t14[(2 * vt8 + m) * T1S4 + ut];
        f2 wl[8], wh[8];
        #pragma unroll
        for (int m = 0; m < 8; ++m) {
            wl[m] = f2{w[m][0], w[m][1]};
            wh[m] = f2{w[m][2], w[m][3]};
        }
        #pragma unroll
        for (int dv = 0; dv < 8; ++dv) {
            const int row = 8 * vt8 + dv;
            if (row < 74) {
                const int k0 = (dv + 1) & 3;
                const int bb = 5 + ((dv + 1) >> 2);
                f2 al = {bc[k0][0], bc[k0][1]};
                f2 ah = {bc[k0][2], bc[k0][3]};
                #pragma unroll
                for (int t = 0; t < 6; ++t) {
                    al += fr[k0 + 4 * t] * wl[bb - t];
                    ah += fr[k0 + 4 * t] * wh[bb - t];
                }
                uint2 pp;
                pp.x = leaky_pk(pkrtz_u32(al[0], al[1]), c02);
                pp.y = leaky_pk(pkrtz_u32(ah[0], ah[1]), c02);
                *(uint2*)(smem + row * ACT_SB + 8 * ut) = pp;
            }
        }
    }
    __syncthreads();

    // ---- C: horizontal downsample via dot2 -> t2t f16 [o][v] (transposed) ----
    {
        // batch 1: rows 0..63, all 256 threads
        const int v = tid & 63, otg = tid >> 6;
        {
            const unsigned* ar = (const unsigned*)(smem + v * ACT_SB + 32 * otg);
            uint4 q0 = *(const uint4*)(ar);
            uint4 q1 = *(const uint4*)(ar + 4);
            uint4 q2 = *(const uint4*)(ar + 8);
            const unsigned dl = ar[12];
            unsigned d[13] = {q0.x,q0.y,q0.z,q0.w, q1.x,q1.y,q1.z,q1.w,
                              q2.x,q2.y,q2.z,q2.w, dl};
            #pragma unroll
            for (int i = 0; i < 8; ++i) {
                float acc = 0.f;
                #pragma unroll
                for (int m = 0; m < 6; ++m)
                    acc = __builtin_amdgcn_fdot2(as_h2(d[i + m]), gpk[m], acc, false);
                _Float16 hv = (_Float16)acc;
                *(_Float16*)(smem + T1_OFF + (8*otg + i) * T2T_SB + 2*v) = hv;
            }
        }
        // batch 2: rows 64..73
        if (tid < 64) {
            const int otg2 = tid >> 4, vr = tid & 15;
            if (vr < 10) {
                const int v2 = 64 + vr;
                const unsigned* ar = (const unsigned*)(smem + v2 * ACT_SB + 32 * otg2);
                uint4 q0 = *(const uint4*)(ar);
                uint4 q1 = *(const uint4*)(ar + 4);
                uint4 q2 = *(const uint4*)(ar + 8);
                const unsigned dl = ar[12];
                unsigned d[13] = {q0.x,q0.y,q0.z,q0.w, q1.x,q1.y,q1.z,q1.w,
                                  q2.x,q2.y,q2.z,q2.w, dl};
                #pragma unroll
                for (int i = 0; i < 8; ++i) {
                    float acc = 0.f;
                    #pragma unroll
                    for (int m = 0; m < 6; ++m)
                        acc = __builtin_amdgcn_fdot2(as_h2(d[i + m]), gpk[m], acc, false);
                    _Float16 hv = (_Float16)acc;
                    *(_Float16*)(smem + T1_OFF + (8*otg2 + i) * T2T_SB + 2*v2) = hv;
                }
            }
        }
    }
    __syncthreads();

    // ---- D: vertical downsample via dot2, *sqrt2, store to global ----
    {
        const int oy0 = ty * 32, ox0 = tx * 32;
        float* op = out + (size_t)plane * (236 * 236);
        const int ox = tid & 31, g = tid >> 5;
        const unsigned* tr = (const unsigned*)(smem + T1_OFF + ox * T2T_SB + 16 * g);
        uint4 q0 = *(const uint4*)(tr);
        uint4 q1 = *(const uint4*)(tr + 4);
        const unsigned dl = tr[8];
        unsigned d[9] = {q0.x, q0.y, q0.z, q0.w, q1.x, q1.y, q1.z, q1.w, dl};
        const int oxg = ox0 + ox;
        if (!edge) {
            #pragma unroll
            for (int dv = 0; dv < 4; ++dv) {
                float acc = 0.f;
                #pragma unroll
                for (int m = 0; m < 6; ++m)
                    acc = __builtin_amdgcn_fdot2(as_h2(d[dv + m]), gpk[m], acc, false);
                op[(oy0 + 4 * g + dv) * 236 + oxg] = acc * 1.4142135623730951f;
            }
        } else {
            #pragma unroll
            for (int dv = 0; dv < 4; ++dv) {
                float acc = 0.f;
                #pragma unroll
                for (int m = 0; m < 6; ++m)
                    acc = __builtin_amdgcn_fdot2(as_h2(d[dv + m]), gpk[m], acc, false);
                const int oy = oy0 + 4 * g + dv;
                if (oy < 236 && oxg < 236)
                    op[oy * 236 + oxg] = acc * 1.4142135623730951f;
            }
        }
    }
}

extern "C" void kernel_launch(void* const* d_in, const int* in_sizes, int n_in,
                              void* d_out, int out_size, void* d_ws, size_t ws_size,
                              hipStream_t stream) {
    const float* x    = (const float*)d_in[0];
    const float* bias = (const float*)d_in[1];
    const float* fup  = (const float*)d_in[2];
    const float* fdn  = (const float*)d_in[3];
    float* out = (float*)d_out;

    dim3 grid(1024 * 64);
    dim3 block(256);
    afa_kernel<<<grid, block, 0, stream>>>(x, bias, fup, fdn, out);
}